// Round 15
// baseline (366.202 us; speedup 1.0000x reference)
//
#include <hip/hip_runtime.h>
#include <hip/hip_bf16.h>
#include <stdint.h>

// GPTQ 4-bit linear: y = x @ dequant(qweight,qzeros,scales) + bias
// x: [4,2048,4096] fp32 -> M=8192 rows; qweight [512,4096] i32 (8 k-nibbles/word);
// qzeros [32,512] i32 (8 n-nibbles/word, z=nib+1); scales [32,4096] f32; out f32.

#define M_TOT 8192
#define N_TOT 4096
#define K_TOT 4096
#define NT    (K_TOT / 64)   // 64 K-tiles of BK=64

using bf16x8 = __attribute__((ext_vector_type(8))) __bf16;
using f32x4  = __attribute__((ext_vector_type(4))) float;

__device__ __forceinline__ unsigned short f2bf(float f) {
  unsigned u = __builtin_bit_cast(unsigned, f);
  u += 0x7fffu + ((u >> 16) & 1u);   // RNE
  return (unsigned short)(u >> 16);
}

// ---------------- x: fp32 -> bf16 ----------------
__global__ void cvt_x_kernel(const float* __restrict__ x,
                             unsigned short* __restrict__ xb, int n) {
  int stride = gridDim.x * blockDim.x * 8;
  for (int i = (blockIdx.x * blockDim.x + threadIdx.x) * 8; i < n; i += stride) {
    float4 a = *reinterpret_cast<const float4*>(x + i);
    float4 b = *reinterpret_cast<const float4*>(x + i + 4);
    unsigned short o[8] = {f2bf(a.x), f2bf(a.y), f2bf(a.z), f2bf(a.w),
                           f2bf(b.x), f2bf(b.y), f2bf(b.z), f2bf(b.w)};
    *reinterpret_cast<uint4*>(xb + i) = *reinterpret_cast<const uint4*>(o);
  }
}

// -------- dequant -> W^T packed in MFMA fragment order (128-tile slicing) ---
// u = bn*65536 + wc*32768 + tt*512 + (n*2+s)*64 + lane; element = u*8 + j.
// Slice (bn,wc) stride = 32768*8 = 262144 elems (r14 bug: was 131072).
// GEMM wave (bn,wc) tile t frag (n,s): lane l holds W^T[nn][k],
// nn = bn*128+wc*64+n*16+(l&15), k = t*64+s*32+(l>>4)*8+j.
__global__ void dequant_pack_kernel(const int* __restrict__ qweight,
                                    const int* __restrict__ qzeros,
                                    const float* __restrict__ scales,
                                    unsigned short* __restrict__ wt) {
  unsigned u = blockIdx.x * blockDim.x + threadIdx.x;  // [0, 2^21)
  int lane = u & 63;
  int fs   = (u >> 6) & 7;          // n*2+s
  int n    = fs >> 1, s = fs & 1;
  int tt   = (u >> 9) & 63;
  int wcb  = (u >> 15) & 1;
  int bn   = u >> 16;               // 0..31
  int nn = bn * 128 + wcb * 64 + n * 16 + (lane & 15);
  int kw = tt * 8 + s * 4 + (lane >> 4);   // packed word along K
  int g  = kw >> 4;
  unsigned w = (unsigned)qweight[kw * N_TOT + nn];
  float sc = scales[g * N_TOT + nn];
  unsigned zw = (unsigned)qzeros[g * (N_TOT / 8) + (nn >> 3)];
  float z = (float)(((zw >> ((nn & 7) * 4)) & 15u) + 1u);
  unsigned short o[8];
#pragma unroll
  for (int j = 0; j < 8; ++j) {
    float v = sc * ((float)((w >> (4 * j)) & 15u) - z);
    o[j] = f2bf(v);
  }
  *reinterpret_cast<uint4*>(wt + (size_t)u * 8) =
      *reinterpret_cast<const uint4*>(o);
}

// -- 128x128 GEMM, 4 waves x (64x64), A via 32KB LDS, B packed global->reg ---
// 3 blocks/CU (reg-limited) so one block's vmcnt/barrier drain overlaps other
// blocks' MFMA bursts — the co-residency axis r5-r13 never varied.
__device__ __forceinline__ void gll16(const unsigned short* g, const unsigned short* l) {
  __builtin_amdgcn_global_load_lds(
      (const __attribute__((address_space(1))) void*)(uintptr_t)g,
      (__attribute__((address_space(3))) void*)(uintptr_t)l, 16, 0, 0);
}

__global__ __launch_bounds__(256, 3) void gemm_small_kernel(
    const unsigned short* __restrict__ A,   // [M_TOT][K_TOT] bf16
    const unsigned short* __restrict__ Bp,  // packed W^T (see dequant_pack)
    const float* __restrict__ bias,
    float* __restrict__ C) {
  __shared__ __align__(16) unsigned short As[2 * 128 * 64];   // 32 KB, A only

  int bid = blockIdx.x;                    // 2048 blocks, %8 == 0
  int swz = (bid & 7) * 256 + (bid >> 3);  // bijective XCD swizzle (T1)
  int bm = swz & 63, bn = swz >> 6;        // 64 x 32 tiles
  int m0 = bm * 128;

  int t = threadIdx.x;                     // 256 threads = 4 waves
  int lane = t & 63;
  int wave = t >> 6;
  int wr = wave >> 1, wc = wave & 1;       // 2 (M) x 2 (N), 64x64 per wave
  int lr = lane & 15, kq = lane >> 4;

  // A staging (round-3 swizzle, 0 conflicts): thread covers physical slot
  // t&7 of rows rowL0 + {0,32} per half; source pre-permuted.
  int rowL0 = t >> 3;                                   // 0..31
  int jlog  = ((t & 7) ^ (rowL0 & 7)) * 8;
  const unsigned short* aG = A + (size_t)(m0 + rowL0) * K_TOT + jlog;

  // A swizzled read base (bytes); s half-select XOR-composed (round-2 lesson).
  unsigned rbA = (unsigned)((wr * 64 + lr) * 128 + ((kq * 16) ^ ((lr & 7) << 4)));

  // B packed base: slice stride 262144 elems (the r14 fix).
  const unsigned short* bW = Bp + (size_t)(bn * 2 + wc) * 262144 + (size_t)lane * 8;

  f32x4 acc[4][4] = {};    // 64 regs
  bf16x8 av[2][2];         // [pingpong][s] — next m-frag, 16 regs
  bf16x8 bh[2][4][2];      // [tile parity][n][s] — 64 regs

#define ASTAGE(tile, h)                                                           \
  do {                                                                            \
    const unsigned short* _g = aG + (size_t)(h) * 64 * K_TOT +                    \
                               (size_t)(tile) * 64;                               \
    const unsigned short* _l = As + ((tile) & 1) * 8192 + (h) * 4096 + t * 8;     \
    gll16(_g, _l);                                                                \
    gll16(_g + (size_t)32 * K_TOT, _l + 2048);                                    \
  } while (0)

#define BLOAD(par, tile)                                                          \
  do {                                                                            \
    const unsigned short* _b = bW + (size_t)(tile) * 4096;                        \
    _Pragma("unroll")                                                             \
    for (int _n = 0; _n < 4; ++_n)                                                \
      _Pragma("unroll")                                                           \
      for (int _s = 0; _s < 2; ++_s)                                              \
        bh[par][_n][_s] = *(const bf16x8*)(_b + (_n * 2 + _s) * 512);             \
  } while (0)

  // Prologue: stage A(0), load B(0) to regs.
  ASTAGE(0, 0);
  ASTAGE(0, 1);
  BLOAD(0, 0);
  asm volatile("s_waitcnt vmcnt(0)" ::: "memory");
  __builtin_amdgcn_s_barrier();
  __builtin_amdgcn_sched_barrier(0);

  // Preload tile-0 m-frag 0.
#pragma unroll
  for (int s = 0; s < 2; ++s)
    av[0][s] = *(const bf16x8*)((const char*)As + (rbA ^ (s * 64)));

#pragma unroll 2
  for (int tt = 0; tt < NT; ++tt) {
    const char* aBuf = (const char*)As + (tt & 1) * 16384;

#pragma unroll
    for (int q = 0; q < 4; ++q) {
      // --- MFMA on m-frag prefetched last phase ---
      __builtin_amdgcn_s_setprio(1);
#pragma unroll
      for (int s = 0; s < 2; ++s)
#pragma unroll
        for (int n = 0; n < 4; ++n)
          acc[q][n] = __builtin_amdgcn_mfma_f32_16x16x32_bf16(
              av[q & 1][s], bh[tt & 1][n][s], acc[q][n], 0, 0, 0);
      __builtin_amdgcn_s_setprio(0);

      // --- prefetch next m-frag (same buffer; A stages write other parity) ---
      if (q < 3) {
#pragma unroll
        for (int s = 0; s < 2; ++s)
          av[(q + 1) & 1][s] = *(const bf16x8*)(
              aBuf + ((rbA + (q + 1) * 2048) ^ (s * 64)));
      }

      // --- issue next tile's loads early ---
      if (q == 0 && tt + 1 < NT) {
        BLOAD((tt + 1) & 1, tt + 1);   // coalesced: 8 x dwordx4, one base
        ASTAGE(tt + 1, 0);
      }
      if (q == 1 && tt + 1 < NT) ASTAGE(tt + 1, 1);

      if (q == 3) {
        // Drain B(t+1) regs + A(t+1) glls (issued >=2 phases ago). One
        // barrier/tile (r10 hazard audit). With 3 blocks/CU this drain
        // overlaps other blocks' MFMA bursts.
        asm volatile("s_waitcnt vmcnt(0)" ::: "memory");
        __builtin_amdgcn_s_barrier();
        __builtin_amdgcn_sched_barrier(0);
        if (tt + 1 < NT) {
          const char* aN = (const char*)As + ((tt + 1) & 1) * 16384;
#pragma unroll
          for (int s = 0; s < 2; ++s)
            av[0][s] = *(const bf16x8*)(aN + (rbA ^ (s * 64)));
        }
      }
    }
  }
#undef ASTAGE
#undef BLOAD

  // Epilogue: C/D layout col=lane&15, row=(lane>>4)*4+reg (m89-verified).
#pragma unroll
  for (int n = 0; n < 4; ++n) {
    int ncol = bn * 128 + wc * 64 + n * 16 + lr;
    float bz = bias[ncol];
#pragma unroll
    for (int m = 0; m < 4; ++m) {
      int mrow = m0 + wr * 64 + m * 16 + kq * 4;
#pragma unroll
      for (int r = 0; r < 4; ++r)
        C[(size_t)(mrow + r) * N_TOT + ncol] = acc[m][n][r] + bz;
    }
  }
}

extern "C" void kernel_launch(void* const* d_in, const int* in_sizes, int n_in,
                              void* d_out, int out_size, void* d_ws, size_t ws_size,
                              hipStream_t stream) {
  const float* x       = (const float*)d_in[0];
  const int*   qweight = (const int*)d_in[1];
  const int*   qzeros  = (const int*)d_in[2];
  const float* scales  = (const float*)d_in[3];
  const float* bias    = (const float*)d_in[4];
  float* out = (float*)d_out;

  const size_t xb_bytes = (size_t)M_TOT * K_TOT * 2;   // 64 MB
  const size_t wt_bytes = (size_t)N_TOT * K_TOT * 2;   // 32 MB
  if (ws_size < xb_bytes + wt_bytes) return;

  unsigned short* Xb = (unsigned short*)d_ws;
  unsigned short* Wt = (unsigned short*)((char*)d_ws + xb_bytes);

  cvt_x_kernel<<<2048, 256, 0, stream>>>(x, Xb, M_TOT * K_TOT);
  dequant_pack_kernel<<<(N_TOT * 512) / 256, 256, 0, stream>>>(qweight, qzeros, scales, Wt);

  dim3 grid((M_TOT / 128) * (N_TOT / 128));  // 2048
  gemm_small_kernel<<<grid, 256, 0, stream>>>(Xb, Wt, bias, out);
}

// Round 16
// 297.569 us; speedup vs baseline: 1.2306x; 1.2306x over previous
//
#include <hip/hip_runtime.h>
#include <hip/hip_bf16.h>
#include <stdint.h>

// GPTQ 4-bit linear: y = x @ dequant(qweight,qzeros,scales) + bias
// x: [4,2048,4096] fp32 -> M=8192 rows; qweight [512,4096] i32 (8 k-nibbles/word);
// qzeros [32,512] i32 (8 n-nibbles/word, z=nib+1); scales [32,4096] f32; out f32.

#define M_TOT 8192
#define N_TOT 4096
#define K_TOT 4096
#define NT    (K_TOT / 64)   // 64 K-tiles of BK=64

using bf16x8 = __attribute__((ext_vector_type(8))) __bf16;
using f32x4  = __attribute__((ext_vector_type(4))) float;

__device__ __forceinline__ unsigned short f2bf(float f) {
  unsigned u = __builtin_bit_cast(unsigned, f);
  u += 0x7fffu + ((u >> 16) & 1u);   // RNE
  return (unsigned short)(u >> 16);
}

// ---------------- x: fp32 -> bf16 ----------------
__global__ void cvt_x_kernel(const float* __restrict__ x,
                             unsigned short* __restrict__ xb, int n) {
  int stride = gridDim.x * blockDim.x * 8;
  for (int i = (blockIdx.x * blockDim.x + threadIdx.x) * 8; i < n; i += stride) {
    float4 a = *reinterpret_cast<const float4*>(x + i);
    float4 b = *reinterpret_cast<const float4*>(x + i + 4);
    unsigned short o[8] = {f2bf(a.x), f2bf(a.y), f2bf(a.z), f2bf(a.w),
                           f2bf(b.x), f2bf(b.y), f2bf(b.z), f2bf(b.w)};
    *reinterpret_cast<uint4*>(xb + i) = *reinterpret_cast<const uint4*>(o);
  }
}

// ---------------- dequant -> W^T [N][K] bf16 ----------------
__global__ void dequant_wt_kernel(const int* __restrict__ qweight,
                                  const int* __restrict__ qzeros,
                                  const float* __restrict__ scales,
                                  unsigned short* __restrict__ wt) {
  int t = blockIdx.x * blockDim.x + threadIdx.x;  // [0, N_TOT*512)
  int nn = t >> 9;
  int kw = t & 511;
  int g  = kw >> 4;
  unsigned w = (unsigned)qweight[kw * N_TOT + nn];
  float s = scales[g * N_TOT + nn];
  unsigned zw = (unsigned)qzeros[g * (N_TOT / 8) + (nn >> 3)];
  float z = (float)(((zw >> ((nn & 7) * 4)) & 15u) + 1u);
  unsigned short o[8];
#pragma unroll
  for (int j = 0; j < 8; ++j) {
    float v = s * ((float)((w >> (4 * j)) & 15u) - z);
    o[j] = f2bf(v);
  }
  *reinterpret_cast<uint4*>(wt + (size_t)nn * K_TOT + kw * 8) =
      *reinterpret_cast<const uint4*>(o);
}

// -- 256x256 GEMM, faithful 8-phase template (2 K-tiles/iter unrolled) -------
// Per K-tile: 4 phases, each {reads?; stage 1 half; barrier; lgkm(0); 16 MFMA;
// barrier}. Reads concentrated at p1 (own mg1/ng1) and p4 (next tile mg0/ng0),
// each 12 ds_read_b128. vmcnt(4) at p3 (before barrier2) retires ALL of tile
// t+1 so p4's cross-tile reads are safe after p3's barrier. The per-phase
// lgkm(0) is WAR-load-bearing: it proves all reads of a freed region COMPLETED
// before the barrier that precedes its restage.
__device__ __forceinline__ void gll16(const unsigned short* g, const unsigned short* l) {
  __builtin_amdgcn_global_load_lds(
      (const __attribute__((address_space(1))) void*)(uintptr_t)g,
      (__attribute__((address_space(3))) void*)(uintptr_t)l, 16, 0, 0);
}

__global__ __launch_bounds__(512, 2) void gemm_tmpl_kernel(
    const unsigned short* __restrict__ A,   // [M_TOT][K_TOT] bf16
    const unsigned short* __restrict__ B,   // [N_TOT][K_TOT] bf16 (W^T)
    const float* __restrict__ bias,
    float* __restrict__ C) {
  __shared__ __align__(16) unsigned short As[2 * 256 * 64];   // 64 KB
  __shared__ __align__(16) unsigned short Bs[2 * 256 * 64];   // 64 KB

  int bid = blockIdx.x;                    // 512 blocks, 512 % 8 == 0
  int swz = (bid & 7) * 64 + (bid >> 3);   // bijective XCD swizzle (T1)
  int bm = swz & 31, bn = swz >> 5;        // 32 x 16 tiles
  int m0 = bm * 256, n0 = bn * 256;

  int t = threadIdx.x;
  int lane = t & 63;
  int wave = t >> 6;                       // 8 waves
  int wr = wave >> 2, wc = wave & 3;       // 2 (M) x 4 (N)
  int lr = lane & 15, kq = lane >> 4;

  // Staging (round-3 verified, 0 conflicts): physical chunk p = t&7 of rows
  // rowL0, rowL0+64; source pre-permuted j_log = (t&7) ^ (rowL0&7).
  int rowL0 = t >> 3;
  int jlog  = ((t & 7) ^ (rowL0 & 7)) * 8;
  const unsigned short* aG = A + (size_t)(m0 + rowL0) * K_TOT + jlog;
  const unsigned short* bG = B + (size_t)(n0 + rowL0) * K_TOT + jlog;

  // Swizzled read bases; s half-select composed with XOR (round-2 lesson).
  unsigned rbA = (unsigned)((wr * 128 + lr) * 128 + ((kq * 16) ^ ((lr & 7) << 4)));
  unsigned rbB = (unsigned)((wc * 64  + lr) * 128 + ((kq * 16) ^ ((lr & 7) << 4)));

  f32x4 acc[8][4] = {};
  bf16x8 avX[4][2], avY[4][2];   // m-frags 0-3 / 4-7, [frag][k-half]
  bf16x8 bhX[2][2], bhY[2][2];   // n-frags 0-1 / 2-3

#define STAGE(matG, ldsArr, tile, h)                                              \
  do {                                                                            \
    const unsigned short* _g = (matG) + (size_t)(h) * 128 * K_TOT +               \
                               (size_t)(tile) * 64;                               \
    const unsigned short* _l = (ldsArr) + ((tile) & 1) * 16384 + (h) * 8192 +     \
                               t * 8;                                             \
    gll16(_g, _l);                                                                \
    gll16(_g + (size_t)64 * K_TOT, _l + 4096);                                    \
  } while (0)

#define READ_A(DST, BUF, MOFF)                                                    \
  _Pragma("unroll")                                                               \
  for (int _j = 0; _j < 4; ++_j)                                                  \
    _Pragma("unroll")                                                             \
    for (int _s = 0; _s < 2; ++_s)                                                \
      DST[_j][_s] = *(const bf16x8*)((BUF) +                                      \
          ((rbA + ((MOFF) + _j) * 2048) ^ (_s * 64)));

#define READ_B(DST, BUF, NOFF)                                                    \
  _Pragma("unroll")                                                               \
  for (int _n = 0; _n < 2; ++_n)                                                  \
    _Pragma("unroll")                                                             \
    for (int _s = 0; _s < 2; ++_s)                                                \
      DST[_n][_s] = *(const bf16x8*)((BUF) +                                      \
          ((rbB + ((NOFF) + _n) * 2048) ^ (_s * 64)));

#define MFMA16(AV, BH, MB, NB)                                                    \
  _Pragma("unroll")                                                               \
  for (int _s = 0; _s < 2; ++_s)                                                  \
    _Pragma("unroll")                                                             \
    for (int _m = 0; _m < 4; ++_m)                                                \
      _Pragma("unroll")                                                           \
      for (int _n = 0; _n < 2; ++_n)                                              \
        acc[(MB) + _m][(NB) + _n] = __builtin_amdgcn_mfma_f32_16x16x32_bf16(      \
            AV[_m][_s], BH[_n][_s], acc[(MB) + _m][(NB) + _n], 0, 0, 0);

#define PHASE_SYNC_IN()                                                           \
  __builtin_amdgcn_sched_barrier(0);                                              \
  __builtin_amdgcn_s_barrier();                                                   \
  asm volatile("s_waitcnt lgkmcnt(0)" ::: "memory");                              \
  __builtin_amdgcn_sched_barrier(0)

  // Prologue: t0 all 4 halves + t1 {A.h0, A.h1, B.h0} = 7 halves (14 glls).
  STAGE(aG, As, 0, 0);
  STAGE(aG, As, 0, 1);
  STAGE(bG, Bs, 0, 0);
  STAGE(bG, Bs, 0, 1);
  STAGE(aG, As, 1, 0);
  STAGE(aG, As, 1, 1);
  STAGE(bG, Bs, 1, 0);
  asm volatile("s_waitcnt vmcnt(6)" ::: "memory");  // t0 resident; t1 in flight
  __builtin_amdgcn_s_barrier();
  __builtin_amdgcn_sched_barrier(0);
  READ_A(avX, (const char*)As, 0);   // t0.mg0
  READ_B(bhX, (const char*)Bs, 0);   // t0.ng0

#pragma unroll 2
  for (int tt = 0; tt < NT; ++tt) {
    const char* aBuf = (const char*)As + (tt & 1) * 32768;
    const char* bBuf = (const char*)Bs + (tt & 1) * 32768;

    // ---- p1: read tt.mg1/ng1 (12); stage (tt+1).B.h1; MFMA mg0ng0 ----
    READ_A(avY, aBuf, 4);
    READ_B(bhY, bBuf, 2);
    if (tt + 1 < NT) STAGE(bG, Bs, tt + 1, 1);
    PHASE_SYNC_IN();
    __builtin_amdgcn_s_setprio(1);
    MFMA16(avX, bhX, 0, 0);
    __builtin_amdgcn_s_setprio(0);
    __builtin_amdgcn_s_barrier();

    // ---- p2: stage (tt+2).A.h0; MFMA mg1ng0 ----
    if (tt + 2 < NT) STAGE(aG, As, tt + 2, 0);
    PHASE_SYNC_IN();
    __builtin_amdgcn_s_setprio(1);
    MFMA16(avY, bhX, 4, 0);
    __builtin_amdgcn_s_setprio(0);
    __builtin_amdgcn_s_barrier();

    // ---- p3: stage (tt+2).A.h1; MFMA mg0ng1; vmcnt retires tile tt+1 ----
    if (tt + 2 < NT) STAGE(aG, As, tt + 2, 1);
    PHASE_SYNC_IN();
    __builtin_amdgcn_s_setprio(1);
    MFMA16(avX, bhY, 0, 2);
    __builtin_amdgcn_s_setprio(0);
    // Ledger (steady): in flight = (tt+1).{A.h1,B.h0,B.h1} + (tt+2).{A.h0,
    // A.h1} + leftover (tt+1).A.h0 pair -> vmcnt(4) retires ALL of tt+1,
    // leaves (tt+2).A halves. Barrier below gives cross-wave visibility
    // BEFORE p4's reads (the checkpoint-before-dependent-reads rule).
    if (tt + 2 < NT) asm volatile("s_waitcnt vmcnt(4)" ::: "memory");
    else             asm volatile("s_waitcnt vmcnt(0)" ::: "memory");
    __builtin_amdgcn_s_barrier();

    // ---- p4: read (tt+1).mg0/ng0 (12); stage (tt+2).B.h0; MFMA mg1ng1 ----
    if (tt + 1 < NT) {
      const char* aN = (const char*)As + ((tt + 1) & 1) * 32768;
      const char* bN = (const char*)Bs + ((tt + 1) & 1) * 32768;
      READ_A(avX, aN, 0);
      READ_B(bhX, bN, 0);
    }
    if (tt + 2 < NT) STAGE(bG, Bs, tt + 2, 0);
    PHASE_SYNC_IN();
    __builtin_amdgcn_s_setprio(1);
    MFMA16(avY, bhY, 4, 2);
    __builtin_amdgcn_s_setprio(0);
    __builtin_amdgcn_s_barrier();
  }
#undef STAGE
#undef READ_A
#undef READ_B
#undef MFMA16
#undef PHASE_SYNC_IN

  // Epilogue: C/D layout col=lane&15, row=(lane>>4)*4+reg (m89-verified).
#pragma unroll
  for (int n = 0; n < 4; ++n) {
    int ncol = n0 + wc * 64 + n * 16 + lr;
    float bz = bias[ncol];
#pragma unroll
    for (int m = 0; m < 8; ++m) {
      int mrow = m0 + wr * 128 + m * 16 + kq * 4;
#pragma unroll
      for (int r = 0; r < 4; ++r)
        C[(size_t)(mrow + r) * N_TOT + ncol] = acc[m][n][r] + bz;
    }
  }
}

extern "C" void kernel_launch(void* const* d_in, const int* in_sizes, int n_in,
                              void* d_out, int out_size, void* d_ws, size_t ws_size,
                              hipStream_t stream) {
  const float* x       = (const float*)d_in[0];
  const int*   qweight = (const int*)d_in[1];
  const int*   qzeros  = (const int*)d_in[2];
  const float* scales  = (const float*)d_in[3];
  const float* bias    = (const float*)d_in[4];
  float* out = (float*)d_out;

  const size_t xb_bytes = (size_t)M_TOT * K_TOT * 2;   // 64 MB
  const size_t wt_bytes = (size_t)N_TOT * K_TOT * 2;   // 32 MB
  if (ws_size < xb_bytes + wt_bytes) return;

  unsigned short* Xb = (unsigned short*)d_ws;
  unsigned short* Wt = (unsigned short*)((char*)d_ws + xb_bytes);

  cvt_x_kernel<<<2048, 256, 0, stream>>>(x, Xb, M_TOT * K_TOT);
  dequant_wt_kernel<<<(N_TOT * 512) / 256, 256, 0, stream>>>(qweight, qzeros, scales, Wt);

  dim3 grid((M_TOT / 256) * (N_TOT / 256));  // 512
  gemm_tmpl_kernel<<<grid, 512, 0, stream>>>(Xb, Wt, bias, out);
}

// Round 17
// 280.846 us; speedup vs baseline: 1.3039x; 1.0595x over previous
//
#include <hip/hip_runtime.h>
#include <hip/hip_bf16.h>
#include <stdint.h>

// GPTQ 4-bit linear: y = x @ dequant(qweight,qzeros,scales) + bias
// x: [4,2048,4096] fp32 -> M=8192 rows; qweight [512,4096] i32 (8 k-nibbles/word);
// qzeros [32,512] i32 (8 n-nibbles/word, z=nib+1); scales [32,4096] f32; out f32.

#define M_TOT 8192
#define N_TOT 4096
#define K_TOT 4096
#define NT    (K_TOT / 64)   // 64 K-tiles of BK=64

using bf16x8 = __attribute__((ext_vector_type(8))) __bf16;
using f32x4  = __attribute__((ext_vector_type(4))) float;

__device__ __forceinline__ unsigned short f2bf(float f) {
  unsigned u = __builtin_bit_cast(unsigned, f);
  u += 0x7fffu + ((u >> 16) & 1u);   // RNE
  return (unsigned short)(u >> 16);
}

// ---------------- x: fp32 -> bf16 ----------------
__global__ void cvt_x_kernel(const float* __restrict__ x,
                             unsigned short* __restrict__ xb, int n) {
  int stride = gridDim.x * blockDim.x * 8;
  for (int i = (blockIdx.x * blockDim.x + threadIdx.x) * 8; i < n; i += stride) {
    float4 a = *reinterpret_cast<const float4*>(x + i);
    float4 b = *reinterpret_cast<const float4*>(x + i + 4);
    unsigned short o[8] = {f2bf(a.x), f2bf(a.y), f2bf(a.z), f2bf(a.w),
                           f2bf(b.x), f2bf(b.y), f2bf(b.z), f2bf(b.w)};
    *reinterpret_cast<uint4*>(xb + i) = *reinterpret_cast<const uint4*>(o);
  }
}

// ---------------- dequant -> W^T [N][K] bf16 ----------------
__global__ void dequant_wt_kernel(const int* __restrict__ qweight,
                                  const int* __restrict__ qzeros,
                                  const float* __restrict__ scales,
                                  unsigned short* __restrict__ wt) {
  int t = blockIdx.x * blockDim.x + threadIdx.x;  // [0, N_TOT*512)
  int nn = t >> 9;
  int kw = t & 511;
  int g  = kw >> 4;
  unsigned w = (unsigned)qweight[kw * N_TOT + nn];
  float s = scales[g * N_TOT + nn];
  unsigned zw = (unsigned)qzeros[g * (N_TOT / 8) + (nn >> 3)];
  float z = (float)(((zw >> ((nn & 7) * 4)) & 15u) + 1u);
  unsigned short o[8];
#pragma unroll
  for (int j = 0; j < 8; ++j) {
    float v = s * ((float)((w >> (4 * j)) & 15u) - z);
    o[j] = f2bf(v);
  }
  *reinterpret_cast<uint4*>(wt + (size_t)nn * K_TOT + kw * 8) =
      *reinterpret_cast<const uint4*>(o);
}

// -- 256x256 GEMM, r10 structure with the cross-read burst moved under q3 ----
// Barriers at q2-end/q3-end; next-tile operand reads issue at q2-end and hide
// under q3's MFMA cluster (r10 had them exposed after the q3 barrier).
__device__ __forceinline__ void gll16(const unsigned short* g, const unsigned short* l) {
  __builtin_amdgcn_global_load_lds(
      (const __attribute__((address_space(1))) void*)(uintptr_t)g,
      (__attribute__((address_space(3))) void*)(uintptr_t)l, 16, 0, 0);
}

__global__ __launch_bounds__(512, 2) void gemm_hoist_kernel(
    const unsigned short* __restrict__ A,   // [M_TOT][K_TOT] bf16
    const unsigned short* __restrict__ B,   // [N_TOT][K_TOT] bf16 (W^T)
    const float* __restrict__ bias,
    float* __restrict__ C) {
  __shared__ __align__(16) unsigned short As[2 * 256 * 64];   // 64 KB
  __shared__ __align__(16) unsigned short Bs[2 * 256 * 64];   // 64 KB

  int bid = blockIdx.x;                    // 512 blocks, 512 % 8 == 0
  int swz = (bid & 7) * 64 + (bid >> 3);   // bijective XCD swizzle (T1)
  int bm = swz & 31, bn = swz >> 5;        // 32 x 16 tiles
  int m0 = bm * 256, n0 = bn * 256;

  int t = threadIdx.x;
  int lane = t & 63;
  int wave = t >> 6;                       // 8 waves
  int wr = wave >> 2, wc = wave & 3;       // 2 (M) x 4 (N)
  int lr = lane & 15, kq = lane >> 4;

  // Staging (round-3 verified, 0 conflicts): physical chunk p = t&7 of rows
  // rowL0, rowL0+64; source pre-permuted j_log = (t&7) ^ (rowL0&7).
  int rowL0 = t >> 3;
  int jlog  = ((t & 7) ^ (rowL0 & 7)) * 8;
  const unsigned short* aG = A + (size_t)(m0 + rowL0) * K_TOT + jlog;
  const unsigned short* bG = B + (size_t)(n0 + rowL0) * K_TOT + jlog;

  // Swizzled read bases; s half-select composed with XOR (round-2 lesson).
  unsigned rbA = (unsigned)((wr * 128 + lr) * 128 + ((kq * 16) ^ ((lr & 7) << 4)));
  unsigned rbB = (unsigned)((wc * 64  + lr) * 128 + ((kq * 16) ^ ((lr & 7) << 4)));

  f32x4 acc[8][4] = {};
  bf16x8 av[2][2][2];   // [pingpong][mm][s]
  bf16x8 bh[2][4][2];   // [tile parity][n][s]

#define STAGE(matG, ldsArr, tile, h)                                              \
  do {                                                                            \
    const unsigned short* _g = (matG) + (size_t)(h) * 128 * K_TOT +               \
                               (size_t)(tile) * 64;                               \
    const unsigned short* _l = (ldsArr) + ((tile) & 1) * 16384 + (h) * 8192 +     \
                               t * 8;                                             \
    gll16(_g, _l);                                                                \
    gll16(_g + (size_t)64 * K_TOT, _l + 4096);                                    \
  } while (0)

  // Prologue: A(0):4, B(0):4, B(1):4 glls. A(1) stages at tile-0 q0.
  STAGE(aG, As, 0, 0);
  STAGE(aG, As, 0, 1);
  STAGE(bG, Bs, 0, 0);
  STAGE(bG, Bs, 0, 1);
  STAGE(bG, Bs, 1, 0);
  STAGE(bG, Bs, 1, 1);
  asm volatile("s_waitcnt vmcnt(4)" ::: "memory");  // A(0),B(0) landed
  __builtin_amdgcn_s_barrier();
  __builtin_amdgcn_sched_barrier(0);

  // Preload tile-0 operands: bh[0] = B(0), av[0] = A(0) phase-0 frags.
  {
    const char* aB0 = (const char*)As;
    const char* bB0 = (const char*)Bs;
#pragma unroll
    for (int n = 0; n < 4; ++n)
#pragma unroll
      for (int s = 0; s < 2; ++s)
        bh[0][n][s] = *(const bf16x8*)(bB0 + ((rbB + n * 2048) ^ (s * 64)));
#pragma unroll
    for (int mm = 0; mm < 2; ++mm)
#pragma unroll
      for (int s = 0; s < 2; ++s)
        av[0][mm][s] = *(const bf16x8*)(aB0 + ((rbA + mm * 2048) ^ (s * 64)));
  }

#pragma unroll 2
  for (int tt = 0; tt < NT; ++tt) {
    const char* aBuf = (const char*)As + (tt & 1) * 32768;

#pragma unroll
    for (int q = 0; q < 4; ++q) {
      // --- MFMA on operands issued >= 1 phase ago ---
      __builtin_amdgcn_s_setprio(1);
#pragma unroll
      for (int s = 0; s < 2; ++s)
#pragma unroll
        for (int mm = 0; mm < 2; ++mm)
#pragma unroll
          for (int n = 0; n < 4; ++n)
            acc[2 * q + mm][n] = __builtin_amdgcn_mfma_f32_16x16x32_bf16(
                av[q & 1][mm][s], bh[tt & 1][n][s], acc[2 * q + mm][n], 0, 0, 0);
      __builtin_amdgcn_s_setprio(0);

      // --- stage A(t+1) both halves at q0 (WAR-safe: q3-end barrier of t-1
      // proved all waves consumed their av(t-1) reads) ---
      if (q == 0 && tt + 1 < NT) {
        STAGE(aG, As, tt + 1, 0);
        STAGE(aG, As, tt + 1, 1);
      }

      // --- prefetch next phase's A frags (same parity; stages write other) ---
      if (q < 3) {
#pragma unroll
        for (int mm = 0; mm < 2; ++mm)
#pragma unroll
          for (int s = 0; s < 2; ++s)
            av[(q + 1) & 1][mm][s] = *(const bf16x8*)(
                aBuf + ((rbA + (2 * (q + 1) + mm) * 2048) ^ (s * 64)));
      }

      if (q == 2) {
        // q2-end checkpoint: drain B(t+1) (issued t-1 q3, ~3 phases back) and
        // A(t+1) (issued q0, ~2 phases back) -> both > HBM latency. Barrier
        // publishes them, then cross-reads issue HERE and hide under q3 MFMA.
        asm volatile("s_waitcnt vmcnt(0)" ::: "memory");
        __builtin_amdgcn_s_barrier();
        __builtin_amdgcn_sched_barrier(0);
        if (tt + 1 < NT) {
          const char* aN = (const char*)As + ((tt + 1) & 1) * 32768;
          const char* bN = (const char*)Bs + ((tt + 1) & 1) * 32768;
#pragma unroll
          for (int n = 0; n < 4; ++n)
#pragma unroll
            for (int s = 0; s < 2; ++s)
              bh[(tt + 1) & 1][n][s] =
                  *(const bf16x8*)(bN + ((rbB + n * 2048) ^ (s * 64)));
#pragma unroll
          for (int mm = 0; mm < 2; ++mm)
#pragma unroll
            for (int s = 0; s < 2; ++s)
              av[0][mm][s] = *(const bf16x8*)(aN + ((rbA + mm * 2048) ^ (s * 64)));
        }
      }

      if (q == 3) {
        // Stage B(t+2) both halves: q2-end barrier proved all waves executed
        // q0 -> every bh(t) read completed -> overwriting B parity is safe.
        if (tt + 2 < NT) {
          STAGE(bG, Bs, tt + 2, 0);
          STAGE(bG, Bs, tt + 2, 1);
        }
        __builtin_amdgcn_s_barrier();   // q3-end: closes the tile
      }
    }
  }
#undef STAGE

  // Epilogue: C/D layout col=lane&15, row=(lane>>4)*4+reg (m89-verified).
#pragma unroll
  for (int n = 0; n < 4; ++n) {
    int ncol = n0 + wc * 64 + n * 16 + lr;
    float bz = bias[ncol];
#pragma unroll
    for (int m = 0; m < 8; ++m) {
      int mrow = m0 + wr * 128 + m * 16 + kq * 4;
#pragma unroll
      for (int r = 0; r < 4; ++r)
        C[(size_t)(mrow + r) * N_TOT + ncol] = acc[m][n][r] + bz;
    }
  }
}

extern "C" void kernel_launch(void* const* d_in, const int* in_sizes, int n_in,
                              void* d_out, int out_size, void* d_ws, size_t ws_size,
                              hipStream_t stream) {
  const float* x       = (const float*)d_in[0];
  const int*   qweight = (const int*)d_in[1];
  const int*   qzeros  = (const int*)d_in[2];
  const float* scales  = (const float*)d_in[3];
  const float* bias    = (const float*)d_in[4];
  float* out = (float*)d_out;

  const size_t xb_bytes = (size_t)M_TOT * K_TOT * 2;   // 64 MB
  const size_t wt_bytes = (size_t)N_TOT * K_TOT * 2;   // 32 MB
  if (ws_size < xb_bytes + wt_bytes) return;

  unsigned short* Xb = (unsigned short*)d_ws;
  unsigned short* Wt = (unsigned short*)((char*)d_ws + xb_bytes);

  cvt_x_kernel<<<2048, 256, 0, stream>>>(x, Xb, M_TOT * K_TOT);
  dequant_wt_kernel<<<(N_TOT * 512) / 256, 256, 0, stream>>>(qweight, qzeros, scales, Wt);

  dim3 grid((M_TOT / 256) * (N_TOT / 256));  // 512
  gemm_hoist_kernel<<<grid, 512, 0, stream>>>(Xb, Wt, bias, out);
}